// Round 2
// baseline (411.423 us; speedup 1.0000x reference)
//
#include <hip/hip_runtime.h>
#include <math.h>

// BalancedLoss: B=65536 rows, C=512 classes, pos_prop per class.
// loss = mean(bce(pred,target) * w), w depends only on (column, target value).
// Single streaming pass accumulating per-column {S1, Stot, cnt1}, then tiny finalize.
//
// R2: fast softplus via v_exp_f32/v_log_f32 (__expf/__logf) instead of libm
//     log1pf(expf()) — ~5x less VALU work; grid 512->2048 for occupancy.

constexpr int C = 512;
constexpr int C4 = 128;   // float4s per row

__device__ __forceinline__ float softplus_neg_abs(float p) {
    // log(1 + exp(-|p|)) via HW exp/log; |p| >= 0 so arg in (0,1], 1+e in (1,2].
    return __logf(1.0f + __expf(-fabsf(p)));
}

__global__ __launch_bounds__(512) void bl_partial(
    const float4* __restrict__ pred4, const float4* __restrict__ targ4,
    float* __restrict__ acc, int rows_per_block)
{
    const int tid = threadIdx.x;
    const int col4 = tid & (C4 - 1);   // which float4 within the row
    const int rowlane = tid >> 7;      // 0..3 (4 rows in flight per block)
    const long long row0 = (long long)blockIdx.x * rows_per_block;

    float4 a_s1 = {0.f, 0.f, 0.f, 0.f};
    float4 a_st = {0.f, 0.f, 0.f, 0.f};
    float4 a_c1 = {0.f, 0.f, 0.f, 0.f};

    #pragma unroll 8
    for (int r = rowlane; r < rows_per_block; r += 4) {
        size_t idx = (size_t)(row0 + r) * C4 + col4;
        float4 p = pred4[idx];
        float4 t = targ4[idx];
        float b;
        b = fmaxf(p.x, 0.f) + softplus_neg_abs(p.x) - p.x * t.x;
        a_st.x += b; a_s1.x += b * t.x; a_c1.x += t.x;
        b = fmaxf(p.y, 0.f) + softplus_neg_abs(p.y) - p.y * t.y;
        a_st.y += b; a_s1.y += b * t.y; a_c1.y += t.y;
        b = fmaxf(p.z, 0.f) + softplus_neg_abs(p.z) - p.z * t.z;
        a_st.z += b; a_s1.z += b * t.z; a_c1.z += t.z;
        b = fmaxf(p.w, 0.f) + softplus_neg_abs(p.w) - p.w * t.w;
        a_st.w += b; a_s1.w += b * t.w; a_c1.w += t.w;
    }

    // Reduce the 4 rowlanes sharing each column-quad, then one atomic per float.
    __shared__ float4 red[3][512];   // 24 KiB
    red[0][tid] = a_s1;
    red[1][tid] = a_st;
    red[2][tid] = a_c1;
    __syncthreads();
    if (tid < C4) {
        #pragma unroll
        for (int a = 0; a < 3; ++a) {
            float4 v0 = red[a][tid];
            float4 v1 = red[a][tid + 128];
            float4 v2 = red[a][tid + 256];
            float4 v3 = red[a][tid + 384];
            float4 v;
            v.x = v0.x + v1.x + v2.x + v3.x;
            v.y = v0.y + v1.y + v2.y + v3.y;
            v.z = v0.z + v1.z + v2.z + v3.z;
            v.w = v0.w + v1.w + v2.w + v3.w;
            float* base = acc + a * C;   // a=0: S1, a=1: Stot, a=2: cnt1
            atomicAdd(&base[tid * 4 + 0], v.x);
            atomicAdd(&base[tid * 4 + 1], v.y);
            atomicAdd(&base[tid * 4 + 2], v.z);
            atomicAdd(&base[tid * 4 + 3], v.w);
        }
    }
}

__global__ __launch_bounds__(512) void bl_finalize(
    const float* __restrict__ acc, const float* __restrict__ pos_prop,
    float* __restrict__ out, float Bf)
{
    const int tid = threadIdx.x;   // one thread per class
    float s1 = acc[tid];
    float st = acc[C + tid];
    float n1 = acc[2 * C + tid];   // exact integer-valued count
    float bal = pos_prop[tid] * Bf;
    float n0 = Bf - n1;
    float S0 = st - s1;
    float w1, w0;
    if (n1 >= bal) {               // positives are majority
        w1 = bal / n1;                                        // n1 >= bal > 0
        w0 = (n0 > 0.f) ? (Bf - bal) / fmaxf(n0, 1.f) : 1.f;  // reference's guard
    } else {                       // negatives are majority (n0 > B - bal >= 0)
        w0 = bal / n0;
        w1 = (n1 > 0.f) ? (Bf - bal) / fmaxf(n1, 1.f) : 1.f;
    }
    float term = w1 * s1 + w0 * S0;

    // 512-thread reduction: wave64 shuffle, then across 8 waves via LDS.
    #pragma unroll
    for (int off = 32; off > 0; off >>= 1)
        term += __shfl_down(term, off, 64);
    __shared__ float wsum[8];
    if ((tid & 63) == 0) wsum[tid >> 6] = term;
    __syncthreads();
    if (tid == 0) {
        float tot = 0.f;
        #pragma unroll
        for (int i = 0; i < 8; ++i) tot += wsum[i];
        out[0] = tot / (Bf * (float)C);
    }
}

extern "C" void kernel_launch(void* const* d_in, const int* in_sizes, int n_in,
                              void* d_out, int out_size, void* d_ws, size_t ws_size,
                              hipStream_t stream) {
    const float* pred     = (const float*)d_in[0];
    const float* target   = (const float*)d_in[1];
    const float* pos_prop = (const float*)d_in[2];
    float* out = (float*)d_out;
    float* acc = (float*)d_ws;             // 3*C floats = 6 KiB

    const int Brows = in_sizes[0] / C;     // 65536
    const int rpb = 32;                    // rows per block
    const int grid = Brows / rpb;          // 2048 blocks

    hipMemsetAsync(d_ws, 0, 3 * C * sizeof(float), stream);
    bl_partial<<<grid, 512, 0, stream>>>((const float4*)pred, (const float4*)target, acc, rpb);
    bl_finalize<<<1, 512, 0, stream>>>(acc, pos_prop, out, (float)Brows);
}

// Round 3
// 289.763 us; speedup vs baseline: 1.4199x; 1.4199x over previous
//
#include <hip/hip_runtime.h>
#include <math.h>

// BalancedLoss: B=65536 rows, C=512 classes, pos_prop per class.
// loss = mean(bce(pred,target) * w), w depends only on (column, target value).
// Single streaming pass accumulating per-column {S1, Stot, cnt1}, then tiny finalize.
//
// R2: fast softplus via v_exp_f32/v_log_f32. R2 regressed: 1536 global atomics
//     per block to the SAME 1536 addresses x 2048 blocks = ~200us of same-address
//     serialization (WRITE_SIZE 4x'd, time tracked it).
// R3: stripe the accumulator across 64 copies (block b -> copy b&63): contention
//     2048 -> 32 per address. Finalize sums the copies.

constexpr int C = 512;
constexpr int C4 = 128;      // float4s per row
constexpr int NCOPY = 64;    // accumulator copies; ws usage = 64*3*512*4 = 384 KiB

__device__ __forceinline__ float softplus_neg_abs(float p) {
    // log(1 + exp(-|p|)) via HW exp/log; arg in (1,2], relative err ~1e-6.
    return __logf(1.0f + __expf(-fabsf(p)));
}

__global__ __launch_bounds__(512) void bl_partial(
    const float4* __restrict__ pred4, const float4* __restrict__ targ4,
    float* __restrict__ acc, int rows_per_block)
{
    const int tid = threadIdx.x;
    const int col4 = tid & (C4 - 1);   // which float4 within the row
    const int rowlane = tid >> 7;      // 0..3 (4 rows in flight per block)
    const long long row0 = (long long)blockIdx.x * rows_per_block;

    float4 a_s1 = {0.f, 0.f, 0.f, 0.f};
    float4 a_st = {0.f, 0.f, 0.f, 0.f};
    float4 a_c1 = {0.f, 0.f, 0.f, 0.f};

    #pragma unroll 8
    for (int r = rowlane; r < rows_per_block; r += 4) {
        size_t idx = (size_t)(row0 + r) * C4 + col4;
        float4 p = pred4[idx];
        float4 t = targ4[idx];
        float b;
        b = fmaxf(p.x, 0.f) + softplus_neg_abs(p.x) - p.x * t.x;
        a_st.x += b; a_s1.x += b * t.x; a_c1.x += t.x;
        b = fmaxf(p.y, 0.f) + softplus_neg_abs(p.y) - p.y * t.y;
        a_st.y += b; a_s1.y += b * t.y; a_c1.y += t.y;
        b = fmaxf(p.z, 0.f) + softplus_neg_abs(p.z) - p.z * t.z;
        a_st.z += b; a_s1.z += b * t.z; a_c1.z += t.z;
        b = fmaxf(p.w, 0.f) + softplus_neg_abs(p.w) - p.w * t.w;
        a_st.w += b; a_s1.w += b * t.w; a_c1.w += t.w;
    }

    // Reduce the 4 rowlanes sharing each column-quad, then one atomic per float
    // into this block's accumulator stripe (copy = blockIdx & 63).
    __shared__ float4 red[3][512];   // 24 KiB
    red[0][tid] = a_s1;
    red[1][tid] = a_st;
    red[2][tid] = a_c1;
    __syncthreads();
    if (tid < C4) {
        float* copy_base = acc + (size_t)(blockIdx.x & (NCOPY - 1)) * (3 * C);
        #pragma unroll
        for (int a = 0; a < 3; ++a) {
            float4 v0 = red[a][tid];
            float4 v1 = red[a][tid + 128];
            float4 v2 = red[a][tid + 256];
            float4 v3 = red[a][tid + 384];
            float4 v;
            v.x = v0.x + v1.x + v2.x + v3.x;
            v.y = v0.y + v1.y + v2.y + v3.y;
            v.z = v0.z + v1.z + v2.z + v3.z;
            v.w = v0.w + v1.w + v2.w + v3.w;
            float* base = copy_base + a * C;   // a=0: S1, a=1: Stot, a=2: cnt1
            atomicAdd(&base[tid * 4 + 0], v.x);
            atomicAdd(&base[tid * 4 + 1], v.y);
            atomicAdd(&base[tid * 4 + 2], v.z);
            atomicAdd(&base[tid * 4 + 3], v.w);
        }
    }
}

__global__ __launch_bounds__(512) void bl_finalize(
    const float* __restrict__ acc, const float* __restrict__ pos_prop,
    float* __restrict__ out, float Bf)
{
    const int tid = threadIdx.x;   // one thread per class
    float s1 = 0.f, st = 0.f, n1 = 0.f;
    // Sum the 64 striped copies; consecutive tids read consecutive addresses.
    for (int c = 0; c < NCOPY; ++c) {
        const float* base = acc + (size_t)c * (3 * C);
        s1 += base[tid];
        st += base[C + tid];
        n1 += base[2 * C + tid];
    }
    float bal = pos_prop[tid] * Bf;
    float n0 = Bf - n1;
    float S0 = st - s1;
    float w1, w0;
    if (n1 >= bal) {               // positives are majority
        w1 = bal / n1;                                        // n1 >= bal > 0
        w0 = (n0 > 0.f) ? (Bf - bal) / fmaxf(n0, 1.f) : 1.f;  // reference's guard
    } else {                       // negatives are majority (n0 > B - bal >= 0)
        w0 = bal / n0;
        w1 = (n1 > 0.f) ? (Bf - bal) / fmaxf(n1, 1.f) : 1.f;
    }
    float term = w1 * s1 + w0 * S0;

    // 512-thread reduction: wave64 shuffle, then across 8 waves via LDS.
    #pragma unroll
    for (int off = 32; off > 0; off >>= 1)
        term += __shfl_down(term, off, 64);
    __shared__ float wsum[8];
    if ((tid & 63) == 0) wsum[tid >> 6] = term;
    __syncthreads();
    if (tid == 0) {
        float tot = 0.f;
        #pragma unroll
        for (int i = 0; i < 8; ++i) tot += wsum[i];
        out[0] = tot / (Bf * (float)C);
    }
}

extern "C" void kernel_launch(void* const* d_in, const int* in_sizes, int n_in,
                              void* d_out, int out_size, void* d_ws, size_t ws_size,
                              hipStream_t stream) {
    const float* pred     = (const float*)d_in[0];
    const float* target   = (const float*)d_in[1];
    const float* pos_prop = (const float*)d_in[2];
    float* out = (float*)d_out;
    float* acc = (float*)d_ws;             // 64 copies * 3*C floats = 384 KiB

    const int Brows = in_sizes[0] / C;     // 65536
    const int rpb = 32;                    // rows per block
    const int grid = Brows / rpb;          // 2048 blocks

    hipMemsetAsync(d_ws, 0, (size_t)NCOPY * 3 * C * sizeof(float), stream);
    bl_partial<<<grid, 512, 0, stream>>>((const float4*)pred, (const float4*)target, acc, rpb);
    bl_finalize<<<1, 512, 0, stream>>>(acc, pos_prop, out, (float)Brows);
}